// Round 5
// baseline (285.158 us; speedup 1.0000x reference)
//
#include <hip/hip_runtime.h>
#include <hip/hip_bf16.h>
#include <stdint.h>

#define BSZ 32
#define TT 128
#define NAG 16
#define NROW 4096
#define NAR 65536
#define EPSV 1e-6f

typedef __attribute__((ext_vector_type(2))) _Float16 half2v;
typedef _Float16 f16x8 __attribute__((ext_vector_type(8)));
typedef float f32x4 __attribute__((ext_vector_type(4)));

#define MFMA16(a,b,c) __builtin_amdgcn_mfma_f32_16x16x32_f16(a,b,c,0,0,0)

__device__ __forceinline__ float dot2f(uint32_t a, uint32_t b, float c) {
#if __has_builtin(__builtin_amdgcn_fdot2)
    return __builtin_amdgcn_fdot2(__builtin_bit_cast(half2v, a),
                                  __builtin_bit_cast(half2v, b), c, false);
#else
    half2v ha = __builtin_bit_cast(half2v, a);
    half2v hb = __builtin_bit_cast(half2v, b);
    return c + (float)ha.x*(float)hb.x + (float)ha.y*(float)hb.y;
#endif
}

__device__ __forceinline__ uint32_t packh2(float a, float b) {
    union { half2v h; uint32_t u; } cu;
    cu.h.x = (_Float16)a; cu.h.y = (_Float16)b;
    return cu.u;
}

__device__ __forceinline__ float sigm(float x) { return 1.f/(1.f + __expf(-x)); }
__device__ __forceinline__ float tanh_f(float x) { return 1.f - 2.f/(__expf(2.f*x) + 1.f); }

// async 16B global->LDS; dest = wave-uniform base + lane*16 (linear)
__device__ __forceinline__ void gl_lds16(const uint32_t* g, uint32_t* lwb, int lane) {
#if __has_builtin(__builtin_amdgcn_global_load_lds)
    __builtin_amdgcn_global_load_lds(
        (const __attribute__((address_space(1))) uint32_t*)g,
        (__attribute__((address_space(3))) uint32_t*)lwb, 16, 0, 0);
#else
    *(uint4*)(lwb + lane*4) = *(const uint4*)g;
#endif
}

// ---------------- K0: pack Wh -> per-column f16 pairs: WhP[d*768+c] = (Wh[2d][c], Wh[2d+1][c]) ----
__global__ void k_prep_wh(const float* __restrict__ Wh, uint32_t* __restrict__ WhP) {
    int g = blockIdx.x*256 + threadIdx.x;
    if (g >= 768*128) return;
    int d = g / 768, c = g % 768;
    WhP[g] = packh2(Wh[(2*d)*768 + c], Wh[(2*d+1)*768 + c]);
}

// ---------------- cvt: obs -> f16 packed rows [4096][1024] ----
__global__ __launch_bounds__(256)
void k_cvt_obs(const float* __restrict__ obs, uint32_t* __restrict__ obs16) {
    int idx = blockIdx.x*256 + threadIdx.x;
    int r = idx >> 7, q = idx & 127;
    int a = q >> 3, f8 = (q & 7)*8;
    const float* p = obs + ((size_t)r*16 + a)*128 + f8;
    float4 v0 = *(const float4*)p, v1 = *(const float4*)(p+4);
    uint4 o; o.x=packh2(v0.x,v0.y); o.y=packh2(v0.z,v0.w);
    o.z=packh2(v1.x,v1.y); o.w=packh2(v1.z,v1.w);
    *(uint4*)(obs16 + (size_t)idx*4) = o;
}

// ---------------- cvt: state -> f16 [4096][256] ----------------
__global__ __launch_bounds__(256)
void k_cvt_state(const float* __restrict__ st, uint32_t* __restrict__ st16) {
    int idx = blockIdx.x*256 + threadIdx.x;
    int r = idx >> 5, q = idx & 31;
    const float* p = st + (size_t)r*256 + q*8;
    float4 v0 = *(const float4*)p, v1 = *(const float4*)(p+4);
    uint4 o; o.x=packh2(v0.x,v0.y); o.y=packh2(v0.z,v0.w);
    o.z=packh2(v1.x,v1.y); o.w=packh2(v1.z,v1.w);
    *(uint4*)(st16 + (size_t)idx*4) = o;
}

// ---------------- transpose+cvt: src f32 [K][N] -> out u32-packed [N][K/2] ----------
__global__ __launch_bounds__(256)
void k_tr(const float* __restrict__ src, uint32_t* __restrict__ out, int N, int Khalf) {
    __shared__ float t_[64][65];
    int k0 = blockIdx.x*64, n0 = blockIdx.y*64;
    int tid = threadIdx.x;
#pragma unroll
    for (int rep = 0; rep < 4; ++rep) {
        int idx = rep*256 + tid;
        int r = idx >> 4, c4 = (idx & 15)*4;
        float4 v = *(const float4*)(src + (size_t)(k0+r)*N + n0 + c4);
        t_[r][c4] = v.x; t_[r][c4+1] = v.y; t_[r][c4+2] = v.z; t_[r][c4+3] = v.w;
    }
    __syncthreads();
#pragma unroll
    for (int rep = 0; rep < 8; ++rep) {
        int idx = rep*256 + tid;
        int nl = idx >> 5, kp = idx & 31;
        out[(size_t)(n0+nl)*Khalf + (k0>>1) + kp] = packh2(t_[kp*2][nl], t_[kp*2+1][nl]);
    }
}

// ---------------- MFMA f16 GEMM: C[M,N] = A16[M,K] @ BT16[N,K]^T + bias ----------------
__global__ __launch_bounds__(256, 2)
void k_xg(const uint32_t* __restrict__ A16, const uint32_t* __restrict__ BT16,
          const float* __restrict__ bias, float* __restrict__ Cp,
          int N, int K, int nTilesN)
{
    __shared__ __align__(16) uint32_t lds[2][8192];
    int nwg = gridDim.x;
    int bid = blockIdx.x;
    int qq = nwg >> 3;
    int logical = (bid & 7)*qq + (bid >> 3);
    int bm = logical / nTilesN, bn = logical % nTilesN;
    int m0 = bm*128, n0 = bn*128;
    int tid = threadIdx.x;
    int lane = tid & 63, wave = tid >> 6;
    int wr = wave >> 1, wc = wave & 1;
    int Ku = K >> 1;

    f32x4 acc[4][4];
#pragma unroll
    for (int i = 0; i < 4; ++i)
#pragma unroll
        for (int j = 0; j < 4; ++j) acc[i][j] = (f32x4){0.f,0.f,0.f,0.f};

    auto STAGE = [&](int buf, int k0) {
#pragma unroll
        for (int i = 0; i < 8; ++i) {
            int c = i*256 + tid;
            int cr = c & 1023;
            int row = cr >> 3, kq = cr & 7;
            const uint32_t* src;
            if (c < 1024) src = A16 + (size_t)(m0+row)*Ku + (k0>>1) + ((kq ^ (row&7))<<2);
            else          src = BT16 + (size_t)(n0+row)*Ku + (k0>>1) + ((kq ^ (row&7))<<2);
            gl_lds16(src, &lds[buf][(size_t)((i*256 + (wave<<6))<<2)], lane);
        }
    };

    STAGE(0, 0);
    __syncthreads();
    int NT = K >> 6;
    for (int t = 0; t < NT; ++t) {
        int cur = t & 1;
        if (t + 1 < NT) STAGE(cur ^ 1, (t+1) << 6);
        const uint32_t* Ab = &lds[cur][0];
        const uint32_t* Bb = &lds[cur][4096];
#pragma unroll
        for (int kk = 0; kk < 2; ++kk) {
            f16x8 af[4], bf[4];
#pragma unroll
            for (int im = 0; im < 4; ++im) {
                int row = wr*64 + im*16 + (lane & 15);
                int ck = (kk*4 + (lane >> 4)) ^ (row & 7);
                af[im] = *(const f16x8*)(Ab + row*32 + ck*4);
            }
#pragma unroll
            for (int in = 0; in < 4; ++in) {
                int row = wc*64 + in*16 + (lane & 15);
                int ck = (kk*4 + (lane >> 4)) ^ (row & 7);
                bf[in] = *(const f16x8*)(Bb + row*32 + ck*4);
            }
#pragma unroll
            for (int im = 0; im < 4; ++im)
#pragma unroll
                for (int in = 0; in < 4; ++in)
                    acc[im][in] = MFMA16(af[im], bf[in], acc[im][in]);
        }
        __syncthreads();
    }
#pragma unroll
    for (int im = 0; im < 4; ++im)
#pragma unroll
        for (int in = 0; in < 4; ++in) {
            int col = n0 + wc*64 + in*16 + (lane & 15);
            float bv = bias[col];
#pragma unroll
            for (int r = 0; r < 4; ++r) {
                int row = m0 + wr*64 + im*16 + (lane >> 4)*4 + r;
                Cp[(size_t)row*N + col] = acc[im][in][r] + bv;
            }
        }
}

// ---------------- K2: GRU scan — 768 thr, 1 gate-column/thread, minimal live state ----
// thread c<256: r-col c; 256..511: z-col; 512..767: n-col (owns h[c-512] in reg)
// Register budget: 12 waves/WG -> 2048/12 = 170 max. w[128] + ~17 live = ~145.
__global__ __launch_bounds__(768, 3)
void k_scan(const uint32_t* __restrict__ WhP, const float* __restrict__ XG,
            float* __restrict__ h_all)
{
    __shared__ float rz[512];
    __shared__ uint32_t h16s[128];     // h packed f16 pairs (2j, 2j+1)
    const int c = threadIdx.x;
    uint32_t w[128];
#pragma unroll
    for (int d = 0; d < 128; ++d) w[d] = WhP[d*768 + c];
    if (c < 128) h16s[c] = 0u;
    float hreg = 0.f;
    const int j = (c >= 512) ? (c - 512) : 0;
    const float* xp = XG + (size_t)blockIdx.x*TT*768 + c;
    float* hp = h_all + (size_t)blockIdx.x*TT*256 + j;
    float xgc = *xp;
    __syncthreads();
    for (int st = 0; st < TT; ++st) {
        // branchless prefetch of next step's gate input (last iter reads into
        // the adjacent hall region of d_ws -- defined memory, value unused)
        float nxt = xp[768];
        xp += 768;
        float a0 = 0.f, a1 = 0.f, a2 = 0.f, a3 = 0.f;
        const uint4* hq = (const uint4*)h16s;
#pragma unroll
        for (int g = 0; g < 32; ++g) {
            uint4 hv = hq[g];
            a0 = dot2f(hv.x, w[4*g+0], a0);
            a1 = dot2f(hv.y, w[4*g+1], a1);
            a2 = dot2f(hv.z, w[4*g+2], a2);
            a3 = dot2f(hv.w, w[4*g+3], a3);
        }
        float hg = (a0 + a1) + (a2 + a3);
        if (c < 512) rz[c] = sigm(xgc + hg);
        __syncthreads();
        if (c >= 512) {
            float zj = rz[256 + j];
            float ng = tanh_f(xgc + rz[j]*hg);
            float hnew = (1.f - zj)*ng + zj*hreg;
            hreg = hnew;
            union { _Float16 h; uint16_t u; } cu; cu.h = (_Float16)hnew;
            ((uint16_t*)h16s)[j] = cu.u;
            *hp = hnew;
        }
        hp += 256;
        __syncthreads();
        xgc = nxt;
    }
}

// ---------------- K4: hypergraph conv (unchanged) ----------------
__global__ __launch_bounds__(256)
void k_hyper(const float* __restrict__ h_all, const float* __restrict__ obs,
             const float* __restrict__ W_inc, const float* __restrict__ b_inc,
             const float* __restrict__ W_hg,
             float* __restrict__ graphs, uint32_t* __restrict__ emb_pk)
{
    __shared__ float hs[256];
    __shared__ float hm[128];
    __shared__ float rdv[16];
    __shared__ float rde[8];
    __shared__ float xs[16][64];
    __shared__ float msg[8][64];
    __shared__ float outs[16][64];
    int r = blockIdx.x;
    int t = threadIdx.x;
    hs[t] = h_all[(size_t)r*256 + t];
    __syncthreads();
    if (t < 128) {
        float a = b_inc[t];
#pragma unroll 8
        for (int k = 0; k < 256; ++k) a = fmaf(hs[k], W_inc[k*128 + t], a);
        float s = sigm(a);
        hm[t] = s;
        graphs[(size_t)r*128 + t] = s;
    }
    __syncthreads();
    if (t < 16) {
        float s = EPSV;
#pragma unroll
        for (int e = 0; e < 8; ++e) s += hm[t*8 + e];
        rdv[t] = 1.f/sqrtf(s);
    } else if (t >= 64 && t < 72) {
        int e = t - 64;
        float s = EPSV;
#pragma unroll
        for (int a2 = 0; a2 < 16; ++a2) s += hm[a2*8 + e];
        rde[e] = 1.f/s;
    }
    __syncthreads();
    {
        int aa = t >> 4, f4 = t & 15;
        float4 v = *(const float4*)(obs + (size_t)r*2048 + aa*128 + f4*4);
        float sc = rdv[aa];
        *(float4*)&xs[aa][f4*4] = make_float4(v.x*sc, v.y*sc, v.z*sc, v.w*sc);
    }
    __syncthreads();
#pragma unroll
    for (int rep = 0; rep < 2; ++rep) {
        int o = rep*256 + t;
        int e = o >> 6, f = o & 63;
        float s = 0.f;
#pragma unroll
        for (int a2 = 0; a2 < 16; ++a2) s = fmaf(hm[a2*8 + e], xs[a2][f], s);
        msg[e][f] = s * rde[e];
    }
    __syncthreads();
#pragma unroll
    for (int rep = 0; rep < 4; ++rep) {
        int o = rep*256 + t;
        int a2 = o >> 6, f = o & 63;
        float s = 0.f;
#pragma unroll
        for (int e = 0; e < 8; ++e) s = fmaf(hm[a2*8 + e], msg[e][f], s);
        outs[a2][f] = s * rdv[a2];
    }
    __syncthreads();
    {
        int aa = t >> 4, fo0 = (t & 15)*4;
        float s0=0,s1=0,s2=0,s3=0;
#pragma unroll 8
        for (int f = 0; f < 64; ++f) {
            float ov = outs[aa][f];
            float4 wv = *(const float4*)(W_hg + f*64 + fo0);
            s0 = fmaf(ov, wv.x, s0); s1 = fmaf(ov, wv.y, s1);
            s2 = fmaf(ov, wv.z, s2); s3 = fmaf(ov, wv.w, s3);
        }
        s0 = fmaxf(s0,0.f); s1 = fmaxf(s1,0.f); s2 = fmaxf(s2,0.f); s3 = fmaxf(s3,0.f);
        uint2 pk; pk.x = packh2(s0, s1); pk.y = packh2(s2, s3);
        *(uint2*)&emb_pk[((size_t)r*16 + aa)*32 + (t & 15)*2] = pk;
    }
}

// ---------------- K5: fused MLP head, MFMA; 128 rows/block, 8 waves ----------------
__global__ __launch_bounds__(512, 2)
void k_mlp(const uint32_t* __restrict__ emb_pk, const float* __restrict__ S1,
           const float* __restrict__ W1, const uint32_t* __restrict__ W1eT16,
           const uint32_t* __restrict__ W2T16,
           const float* __restrict__ b2, const float* __restrict__ W3,
           const float* __restrict__ b3, float* __restrict__ qout)
{
    __shared__ __align__(16) uint32_t x1s[16384];
    __shared__ __align__(16) uint32_t wbuf[2][8192];
    __shared__ float qpart[128][2];
    int tid = threadIdx.x;
    int lane = tid & 63, wave = tid >> 6;
    int wr = wave >> 1, wc = wave & 1;
    int rowbase = blockIdx.x * 128;

#pragma unroll
    for (int i = 0; i < 4; ++i) {
        int c = i*512 + tid;
        int row = c >> 3, kq = c & 7;
        gl_lds16(W1eT16 + (size_t)row*32 + ((kq ^ (row&7))<<2),
                 &wbuf[0][(size_t)((i*512 + (wave<<6))<<2)], lane);
    }
#pragma unroll
    for (int i = 0; i < 2; ++i) {
        int c = i*512 + tid;
        int row = c >> 3, kq = c & 7;
        gl_lds16(emb_pk + (size_t)(rowbase+row)*32 + ((kq ^ (row&7))<<2),
                 &wbuf[1][(size_t)((i*512 + (wave<<6))<<2)], lane);
    }
    f32x4 acc[2][8];
#pragma unroll
    for (int im = 0; im < 2; ++im)
#pragma unroll
        for (int in = 0; in < 8; ++in) {
            int col = wc*128 + in*16 + (lane & 15);
#pragma unroll
            for (int r = 0; r < 4; ++r) {
                int rl = wr*32 + im*16 + (lane >> 4)*4 + r;
                int grow = rowbase + rl;
                acc[im][in][r] = S1[(size_t)(grow >> 4)*256 + col]
                               + W1[(size_t)(256 + (grow & 15))*256 + col];
            }
        }
    __syncthreads();
#pragma unroll
    for (int kk = 0; kk < 2; ++kk) {
        f16x8 af[2], bf[8];
#pragma unroll
        for (int im = 0; im < 2; ++im) {
            int row = wr*32 + im*16 + (lane & 15);
            int ck = (kk*4 + (lane >> 4)) ^ (row & 7);
            af[im] = *(const f16x8*)(&wbuf[1][row*32 + ck*4]);
        }
#pragma unroll
        for (int in = 0; in < 8; ++in) {
            int n = wc*128 + in*16 + (lane & 15);
            int ck = (kk*4 + (lane >> 4)) ^ (n & 7);
            bf[in] = *(const f16x8*)(&wbuf[0][n*32 + ck*4]);
        }
#pragma unroll
        for (int im = 0; im < 2; ++im)
#pragma unroll
            for (int in = 0; in < 8; ++in)
                acc[im][in] = MFMA16(af[im], bf[in], acc[im][in]);
    }
#pragma unroll
    for (int im = 0; im < 2; ++im)
#pragma unroll
        for (int in = 0; in < 8; ++in) {
            int col = wc*128 + in*16 + (lane & 15);
            int chunk = col >> 3, pos = col & 7;
#pragma unroll
            for (int r = 0; r < 4; ++r) {
                int rl = wr*32 + im*16 + (lane >> 4)*4 + r;
                int swc = chunk ^ (rl & 7);
                *((_Float16*)x1s + rl*256 + swc*8 + pos) =
                    (_Float16)fmaxf(acc[im][in][r], 0.f);
                acc[im][in][r] = 0.f;
            }
        }
    __syncthreads();
    auto STAGE_W2 = [&](int buf, int kc) {
#pragma unroll
        for (int i = 0; i < 4; ++i) {
            int c = i*512 + tid;
            int row = c >> 3, kq = c & 7;
            gl_lds16(W2T16 + (size_t)row*128 + kc*32 + ((kq ^ (row&7))<<2),
                     &wbuf[buf][(size_t)((i*512 + (wave<<6))<<2)], lane);
        }
    };
    STAGE_W2(0, 0);
    __syncthreads();
    for (int kc = 0; kc < 4; ++kc) {
        int cur = kc & 1;
        if (kc + 1 < 4) STAGE_W2(cur ^ 1, kc + 1);
#pragma unroll
        for (int kk = 0; kk < 2; ++kk) {
            f16x8 af[2], bf[8];
#pragma unroll
            for (int im = 0; im < 2; ++im) {
                int row = wr*32 + im*16 + (lane & 15);
                int g = kc*8 + kk*4 + (lane >> 4);
                int ck = g ^ (row & 7);
                af[im] = *(const f16x8*)(&x1s[row*128 + ck*4]);
            }
#pragma unroll
            for (int in = 0; in < 8; ++in) {
                int n = wc*128 + in*16 + (lane & 15);
                int ck = (kk*4 + (lane >> 4)) ^ (n & 7);
                bf[in] = *(const f16x8*)(&wbuf[cur][n*32 + ck*4]);
            }
#pragma unroll
            for (int im = 0; im < 2; ++im)
#pragma unroll
                for (int in = 0; in < 8; ++in)
                    acc[im][in] = MFMA16(af[im], bf[in], acc[im][in]);
        }
        __syncthreads();
    }
    float w3v[8], b2v[8];
#pragma unroll
    for (int in = 0; in < 8; ++in) {
        int col = wc*128 + in*16 + (lane & 15);
        w3v[in] = W3[col]; b2v[in] = b2[col];
    }
#pragma unroll
    for (int im = 0; im < 2; ++im)
#pragma unroll
        for (int r = 0; r < 4; ++r) {
            float qp = 0.f;
#pragma unroll
            for (int in = 0; in < 8; ++in)
                qp = fmaf(fmaxf(acc[im][in][r] + b2v[in], 0.f), w3v[in], qp);
            qp += __shfl_xor(qp, 1);
            qp += __shfl_xor(qp, 2);
            qp += __shfl_xor(qp, 4);
            qp += __shfl_xor(qp, 8);
            if ((lane & 15) == 0)
                qpart[wr*32 + im*16 + (lane >> 4)*4 + r][wc] = qp;
        }
    __syncthreads();
    if (tid < 128)
        qout[rowbase + tid] = qpart[tid][0] + qpart[tid][1] + b3[0];
}

extern "C" void kernel_launch(void* const* d_in, const int* in_sizes, int n_in,
                              void* d_out, int out_size, void* d_ws, size_t ws_size,
                              hipStream_t stream)
{
    const float* state = (const float*)d_in[0];
    const float* obs   = (const float*)d_in[1];
    const float* Wx    = (const float*)d_in[2];
    const float* Wh    = (const float*)d_in[3];
    const float* b_gru = (const float*)d_in[4];
    const float* W_inc = (const float*)d_in[5];
    const float* b_inc = (const float*)d_in[6];
    const float* W_hg  = (const float*)d_in[7];
    const float* W1    = (const float*)d_in[8];
    const float* b1    = (const float*)d_in[9];
    const float* W2    = (const float*)d_in[10];
    const float* b2    = (const float*)d_in[11];
    const float* W3    = (const float*)d_in[12];
    const float* b3    = (const float*)d_in[13];
    float* qout   = (float*)d_out;
    float* graphs = (float*)d_out + NAR;

    float* base = (float*)d_ws;
    float* XG        = base;                              // 3,145,728 f
    float* hall      = base + 3145728;                    // 1,048,576 f
    float* S1        = base + 4194304;                    // 1,048,576 f
    uint32_t* emb_pk = (uint32_t*)(base + 5242880);       // 2,097,152 u32
    uint32_t* WhP    = (uint32_t*)(base + 7340032);       //    98,304 u32
    uint32_t* obs16  = (uint32_t*)(base + 7438336);       // 2,097,152 u32
    uint32_t* st16   = (uint32_t*)(base + 9535488);       //   524,288 u32
    uint32_t* WxT16  = (uint32_t*)(base + 10059776);      //   393,216 u32
    uint32_t* W1T16  = (uint32_t*)(base + 10452992);      //    32,768 u32
    uint32_t* W1eT16 = (uint32_t*)(base + 10485760);      //     8,192 u32
    uint32_t* W2T16  = (uint32_t*)(base + 10493952);      //    32,768 u32

    hipLaunchKernelGGL(k_prep_wh, dim3(384), dim3(256), 0, stream, Wh, WhP);
    hipLaunchKernelGGL(k_cvt_obs, dim3(2048), dim3(256), 0, stream, obs, obs16);
    hipLaunchKernelGGL(k_cvt_state, dim3(512), dim3(256), 0, stream, state, st16);
    hipLaunchKernelGGL(k_tr, dim3(16, 12), dim3(256), 0, stream, Wx, WxT16, 768, 512);
    hipLaunchKernelGGL(k_tr, dim3(4, 4), dim3(256), 0, stream, W1, W1T16, 256, 128);
    hipLaunchKernelGGL(k_tr, dim3(1, 4), dim3(256), 0, stream, W1 + 272*256, W1eT16, 256, 32);
    hipLaunchKernelGGL(k_tr, dim3(4, 4), dim3(256), 0, stream, W2, W2T16, 256, 128);
    hipLaunchKernelGGL(k_xg, dim3(192), dim3(256), 0, stream,
                       obs16, WxT16, b_gru, XG, 768, 1024, 6);
    hipLaunchKernelGGL(k_xg, dim3(64), dim3(256), 0, stream,
                       st16, W1T16, b1, S1, 256, 256, 2);
    hipLaunchKernelGGL(k_scan, dim3(32), dim3(768), 0, stream, WhP, XG, hall);
    hipLaunchKernelGGL(k_hyper, dim3(4096), dim3(256), 0, stream,
                       hall, obs, W_inc, b_inc, W_hg, graphs, emb_pk);
    hipLaunchKernelGGL(k_mlp, dim3(512), dim3(512), 0, stream,
                       emb_pk, S1, W1, W1eT16, W2T16, b2, W3, b3, qout);
}

// Round 6
// 266.197 us; speedup vs baseline: 1.0712x; 1.0712x over previous
//
#include <hip/hip_runtime.h>
#include <hip/hip_bf16.h>
#include <stdint.h>

#define BSZ 32
#define TT 128
#define NAG 16
#define NROW 4096
#define NAR 65536
#define EPSV 1e-6f

typedef __attribute__((ext_vector_type(2))) _Float16 half2v;
typedef _Float16 f16x8 __attribute__((ext_vector_type(8)));
typedef float f32x4 __attribute__((ext_vector_type(4)));

#define MFMA16(a,b,c) __builtin_amdgcn_mfma_f32_16x16x32_f16(a,b,c,0,0,0)

__device__ __forceinline__ float dot2f(uint32_t a, uint32_t b, float c) {
#if __has_builtin(__builtin_amdgcn_fdot2)
    return __builtin_amdgcn_fdot2(__builtin_bit_cast(half2v, a),
                                  __builtin_bit_cast(half2v, b), c, false);
#else
    half2v ha = __builtin_bit_cast(half2v, a);
    half2v hb = __builtin_bit_cast(half2v, b);
    return c + (float)ha.x*(float)hb.x + (float)ha.y*(float)hb.y;
#endif
}

__device__ __forceinline__ uint32_t packh2(float a, float b) {
    union { half2v h; uint32_t u; } cu;
    cu.h.x = (_Float16)a; cu.h.y = (_Float16)b;
    return cu.u;
}

__device__ __forceinline__ float sigm(float x) { return 1.f/(1.f + __expf(-x)); }
__device__ __forceinline__ float tanh_f(float x) { return 1.f - 2.f/(__expf(2.f*x) + 1.f); }

// async 16B global->LDS; dest = wave-uniform base + lane*16 (linear)
__device__ __forceinline__ void gl_lds16(const uint32_t* g, uint32_t* lwb, int lane) {
#if __has_builtin(__builtin_amdgcn_global_load_lds)
    __builtin_amdgcn_global_load_lds(
        (const __attribute__((address_space(1))) uint32_t*)g,
        (__attribute__((address_space(3))) uint32_t*)lwb, 16, 0, 0);
#else
    *(uint4*)(lwb + lane*4) = *(const uint4*)g;
#endif
}

// ---------------- K0: pack Wh for scan: flat = kh*49152 + unit*16384 + d*256 + u ----
// value = f16 pair (Wh[k][c], Wh[k+1][c]) with k = kh*128 + 2d, c = unit*256 + u
__global__ void k_prep_wh(const float* __restrict__ Wh, uint32_t* __restrict__ WhP) {
    int g = blockIdx.x*256 + threadIdx.x;
    if (g >= 768*128) return;
    int kh = g / 49152;
    int r2 = g % 49152;
    int unit = r2 / 16384;
    int r3 = r2 % 16384;
    int d = r3 >> 8;
    int u = r3 & 255;
    int k = kh*128 + 2*d;
    int c = unit*256 + u;
    WhP[g] = packh2(Wh[(size_t)k*768 + c], Wh[(size_t)(k+1)*768 + c]);
}

// ---------------- cvt: obs -> f16 packed rows [4096][1024] ----
__global__ __launch_bounds__(256)
void k_cvt_obs(const float* __restrict__ obs, uint32_t* __restrict__ obs16) {
    int idx = blockIdx.x*256 + threadIdx.x;
    int r = idx >> 7, q = idx & 127;
    int a = q >> 3, f8 = (q & 7)*8;
    const float* p = obs + ((size_t)r*16 + a)*128 + f8;
    float4 v0 = *(const float4*)p, v1 = *(const float4*)(p+4);
    uint4 o; o.x=packh2(v0.x,v0.y); o.y=packh2(v0.z,v0.w);
    o.z=packh2(v1.x,v1.y); o.w=packh2(v1.z,v1.w);
    *(uint4*)(obs16 + (size_t)idx*4) = o;
}

// ---------------- cvt: state -> f16 [4096][256] ----------------
__global__ __launch_bounds__(256)
void k_cvt_state(const float* __restrict__ st, uint32_t* __restrict__ st16) {
    int idx = blockIdx.x*256 + threadIdx.x;
    int r = idx >> 5, q = idx & 31;
    const float* p = st + (size_t)r*256 + q*8;
    float4 v0 = *(const float4*)p, v1 = *(const float4*)(p+4);
    uint4 o; o.x=packh2(v0.x,v0.y); o.y=packh2(v0.z,v0.w);
    o.z=packh2(v1.x,v1.y); o.w=packh2(v1.z,v1.w);
    *(uint4*)(st16 + (size_t)idx*4) = o;
}

// ---------------- transpose+cvt: src f32 [K][N] -> out u32-packed [N][K/2] ----------
__global__ __launch_bounds__(256)
void k_tr(const float* __restrict__ src, uint32_t* __restrict__ out, int N, int Khalf) {
    __shared__ float t_[64][65];
    int k0 = blockIdx.x*64, n0 = blockIdx.y*64;
    int tid = threadIdx.x;
#pragma unroll
    for (int rep = 0; rep < 4; ++rep) {
        int idx = rep*256 + tid;
        int r = idx >> 4, c4 = (idx & 15)*4;
        float4 v = *(const float4*)(src + (size_t)(k0+r)*N + n0 + c4);
        t_[r][c4] = v.x; t_[r][c4+1] = v.y; t_[r][c4+2] = v.z; t_[r][c4+3] = v.w;
    }
    __syncthreads();
#pragma unroll
    for (int rep = 0; rep < 8; ++rep) {
        int idx = rep*256 + tid;
        int nl = idx >> 5, kp = idx & 31;
        out[(size_t)(n0+nl)*Khalf + (k0>>1) + kp] = packh2(t_[kp*2][nl], t_[kp*2+1][nl]);
    }
}

// ---------------- MFMA f16 GEMM: C[M,N] = A16[M,K] @ BT16[N,K]^T + bias ----------------
__global__ __launch_bounds__(256, 2)
void k_xg(const uint32_t* __restrict__ A16, const uint32_t* __restrict__ BT16,
          const float* __restrict__ bias, float* __restrict__ Cp,
          int N, int K, int nTilesN)
{
    __shared__ __align__(16) uint32_t lds[2][8192];
    int nwg = gridDim.x;
    int bid = blockIdx.x;
    int qq = nwg >> 3;
    int logical = (bid & 7)*qq + (bid >> 3);
    int bm = logical / nTilesN, bn = logical % nTilesN;
    int m0 = bm*128, n0 = bn*128;
    int tid = threadIdx.x;
    int lane = tid & 63, wave = tid >> 6;
    int wr = wave >> 1, wc = wave & 1;
    int Ku = K >> 1;

    f32x4 acc[4][4];
#pragma unroll
    for (int i = 0; i < 4; ++i)
#pragma unroll
        for (int j = 0; j < 4; ++j) acc[i][j] = (f32x4){0.f,0.f,0.f,0.f};

    auto STAGE = [&](int buf, int k0) {
#pragma unroll
        for (int i = 0; i < 8; ++i) {
            int c = i*256 + tid;
            int cr = c & 1023;
            int row = cr >> 3, kq = cr & 7;
            const uint32_t* src;
            if (c < 1024) src = A16 + (size_t)(m0+row)*Ku + (k0>>1) + ((kq ^ (row&7))<<2);
            else          src = BT16 + (size_t)(n0+row)*Ku + (k0>>1) + ((kq ^ (row&7))<<2);
            gl_lds16(src, &lds[buf][(size_t)((i*256 + (wave<<6))<<2)], lane);
        }
    };

    STAGE(0, 0);
    __syncthreads();
    int NT = K >> 6;
    for (int t = 0; t < NT; ++t) {
        int cur = t & 1;
        if (t + 1 < NT) STAGE(cur ^ 1, (t+1) << 6);
        const uint32_t* Ab = &lds[cur][0];
        const uint32_t* Bb = &lds[cur][4096];
#pragma unroll
        for (int kk = 0; kk < 2; ++kk) {
            f16x8 af[4], bf[4];
#pragma unroll
            for (int im = 0; im < 4; ++im) {
                int row = wr*64 + im*16 + (lane & 15);
                int ck = (kk*4 + (lane >> 4)) ^ (row & 7);
                af[im] = *(const f16x8*)(Ab + row*32 + ck*4);
            }
#pragma unroll
            for (int in = 0; in < 4; ++in) {
                int row = wc*64 + in*16 + (lane & 15);
                int ck = (kk*4 + (lane >> 4)) ^ (row & 7);
                bf[in] = *(const f16x8*)(Bb + row*32 + ck*4);
            }
#pragma unroll
            for (int im = 0; im < 4; ++im)
#pragma unroll
                for (int in = 0; in < 4; ++in)
                    acc[im][in] = MFMA16(af[im], bf[in], acc[im][in]);
        }
        __syncthreads();
    }
#pragma unroll
    for (int im = 0; im < 4; ++im)
#pragma unroll
        for (int in = 0; in < 4; ++in) {
            int col = n0 + wc*64 + in*16 + (lane & 15);
            float bv = bias[col];
#pragma unroll
            for (int r = 0; r < 4; ++r) {
                int row = m0 + wr*64 + im*16 + (lane >> 4)*4 + r;
                Cp[(size_t)row*N + col] = acc[im][in][r] + bv;
            }
        }
}

// ---------------- K2: GRU scan — 512 thr (8 waves, 2/SIMD -> 256-reg budget) ----
// thread (kh=t>>8, u=t&255): cols {u, 256+u, 512+u} for k-half kh. w[192] register-resident.
// Gate tail entirely in thread (0,u): one psum reduce, no cross-thread gather.
__global__ __launch_bounds__(512, 2)
void k_scan(const uint32_t* __restrict__ WhP, const float* __restrict__ XG,
            float* __restrict__ h_all)
{
    __shared__ float psum[2*768];
    __shared__ uint32_t h16s[128];     // h packed f16 pairs (2j, 2j+1)
    const int t = threadIdx.x;
    const int kh = t >> 8;
    const int u  = t & 255;
    uint32_t w[192];
    {
        const uint32_t* wp = WhP + kh*49152 + u;
#pragma unroll
        for (int d = 0; d < 192; ++d) w[d] = wp[d*256];
    }
    if (t < 128) h16s[t] = 0u;
    float hreg = 0.f;
    const float* xp = XG + (size_t)blockIdx.x*TT*768 + u;
    float* hp = h_all + (size_t)blockIdx.x*TT*256 + u;
    float xgr = 0.f, xgz = 0.f, xgn = 0.f;
    if (t < 256) { xgr = xp[0]; xgz = xp[256]; xgn = xp[512]; }
    xp += 768;
    __syncthreads();
    for (int st = 0; st < TT; ++st) {
        // prefetch next step's gate inputs (last iter reads into hall region: defined, unused)
        float nr = 0.f, nz = 0.f, nn = 0.f;
        if (t < 256) { nr = xp[0]; nz = xp[256]; nn = xp[512]; }
        xp += 768;
        float a00=0.f,a01=0.f,a10=0.f,a11=0.f,a20=0.f,a21=0.f;
        const uint4* hq = (const uint4*)&h16s[kh*64];
#pragma unroll
        for (int g = 0; g < 16; ++g) {
            uint4 hv = hq[g];
            a00 = dot2f(hv.x, w[4*g+0],     a00);
            a01 = dot2f(hv.y, w[4*g+1],     a01);
            a00 = dot2f(hv.z, w[4*g+2],     a00);
            a01 = dot2f(hv.w, w[4*g+3],     a01);
            a10 = dot2f(hv.x, w[64+4*g+0],  a10);
            a11 = dot2f(hv.y, w[64+4*g+1],  a11);
            a10 = dot2f(hv.z, w[64+4*g+2],  a10);
            a11 = dot2f(hv.w, w[64+4*g+3],  a11);
            a20 = dot2f(hv.x, w[128+4*g+0], a20);
            a21 = dot2f(hv.y, w[128+4*g+1], a21);
            a20 = dot2f(hv.z, w[128+4*g+2], a20);
            a21 = dot2f(hv.w, w[128+4*g+3], a21);
        }
        psum[kh*768 + u]       = a00 + a01;
        psum[kh*768 + 256 + u] = a10 + a11;
        psum[kh*768 + 512 + u] = a20 + a21;
        __syncthreads();
        if (t < 256) {
            float hr = psum[u]       + psum[768 + u];
            float hz = psum[256 + u] + psum[768 + 256 + u];
            float hn = psum[512 + u] + psum[768 + 512 + u];
            float rg = sigm(xgr + hr);
            float zg = sigm(xgz + hz);
            float ng = tanh_f(xgn + rg*hn);
            float hnew = (1.f - zg)*ng + zg*hreg;
            hreg = hnew;
            union { _Float16 h; uint16_t v; } cu; cu.h = (_Float16)hnew;
            ((uint16_t*)h16s)[u] = cu.v;
            *hp = hnew;
        }
        hp += 256;
        __syncthreads();
        xgr = nr; xgz = nz; xgn = nn;
    }
}

// ---------------- K4: hypergraph conv (unchanged) ----------------
__global__ __launch_bounds__(256)
void k_hyper(const float* __restrict__ h_all, const float* __restrict__ obs,
             const float* __restrict__ W_inc, const float* __restrict__ b_inc,
             const float* __restrict__ W_hg,
             float* __restrict__ graphs, uint32_t* __restrict__ emb_pk)
{
    __shared__ float hs[256];
    __shared__ float hm[128];
    __shared__ float rdv[16];
    __shared__ float rde[8];
    __shared__ float xs[16][64];
    __shared__ float msg[8][64];
    __shared__ float outs[16][64];
    int r = blockIdx.x;
    int t = threadIdx.x;
    hs[t] = h_all[(size_t)r*256 + t];
    __syncthreads();
    if (t < 128) {
        float a = b_inc[t];
#pragma unroll 8
        for (int k = 0; k < 256; ++k) a = fmaf(hs[k], W_inc[k*128 + t], a);
        float s = sigm(a);
        hm[t] = s;
        graphs[(size_t)r*128 + t] = s;
    }
    __syncthreads();
    if (t < 16) {
        float s = EPSV;
#pragma unroll
        for (int e = 0; e < 8; ++e) s += hm[t*8 + e];
        rdv[t] = 1.f/sqrtf(s);
    } else if (t >= 64 && t < 72) {
        int e = t - 64;
        float s = EPSV;
#pragma unroll
        for (int a2 = 0; a2 < 16; ++a2) s += hm[a2*8 + e];
        rde[e] = 1.f/s;
    }
    __syncthreads();
    {
        int aa = t >> 4, f4 = t & 15;
        float4 v = *(const float4*)(obs + (size_t)r*2048 + aa*128 + f4*4);
        float sc = rdv[aa];
        *(float4*)&xs[aa][f4*4] = make_float4(v.x*sc, v.y*sc, v.z*sc, v.w*sc);
    }
    __syncthreads();
#pragma unroll
    for (int rep = 0; rep < 2; ++rep) {
        int o = rep*256 + t;
        int e = o >> 6, f = o & 63;
        float s = 0.f;
#pragma unroll
        for (int a2 = 0; a2 < 16; ++a2) s = fmaf(hm[a2*8 + e], xs[a2][f], s);
        msg[e][f] = s * rde[e];
    }
    __syncthreads();
#pragma unroll
    for (int rep = 0; rep < 4; ++rep) {
        int o = rep*256 + t;
        int a2 = o >> 6, f = o & 63;
        float s = 0.f;
#pragma unroll
        for (int e = 0; e < 8; ++e) s = fmaf(hm[a2*8 + e], msg[e][f], s);
        outs[a2][f] = s * rdv[a2];
    }
    __syncthreads();
    {
        int aa = t >> 4, fo0 = (t & 15)*4;
        float s0=0,s1=0,s2=0,s3=0;
#pragma unroll 8
        for (int f = 0; f < 64; ++f) {
            float ov = outs[aa][f];
            float4 wv = *(const float4*)(W_hg + f*64 + fo0);
            s0 = fmaf(ov, wv.x, s0); s1 = fmaf(ov, wv.y, s1);
            s2 = fmaf(ov, wv.z, s2); s3 = fmaf(ov, wv.w, s3);
        }
        s0 = fmaxf(s0,0.f); s1 = fmaxf(s1,0.f); s2 = fmaxf(s2,0.f); s3 = fmaxf(s3,0.f);
        uint2 pk; pk.x = packh2(s0, s1); pk.y = packh2(s2, s3);
        *(uint2*)&emb_pk[((size_t)r*16 + aa)*32 + (t & 15)*2] = pk;
    }
}

// ---------------- K5: fused MLP head, MFMA; 128 rows/block, 8 waves ----------------
__global__ __launch_bounds__(512, 2)
void k_mlp(const uint32_t* __restrict__ emb_pk, const float* __restrict__ S1,
           const float* __restrict__ W1, const uint32_t* __restrict__ W1eT16,
           const uint32_t* __restrict__ W2T16,
           const float* __restrict__ b2, const float* __restrict__ W3,
           const float* __restrict__ b3, float* __restrict__ qout)
{
    __shared__ __align__(16) uint32_t x1s[16384];
    __shared__ __align__(16) uint32_t wbuf[2][8192];
    __shared__ float qpart[128][2];
    int tid = threadIdx.x;
    int lane = tid & 63, wave = tid >> 6;
    int wr = wave >> 1, wc = wave & 1;
    int rowbase = blockIdx.x * 128;

#pragma unroll
    for (int i = 0; i < 4; ++i) {
        int c = i*512 + tid;
        int row = c >> 3, kq = c & 7;
        gl_lds16(W1eT16 + (size_t)row*32 + ((kq ^ (row&7))<<2),
                 &wbuf[0][(size_t)((i*512 + (wave<<6))<<2)], lane);
    }
#pragma unroll
    for (int i = 0; i < 2; ++i) {
        int c = i*512 + tid;
        int row = c >> 3, kq = c & 7;
        gl_lds16(emb_pk + (size_t)(rowbase+row)*32 + ((kq ^ (row&7))<<2),
                 &wbuf[1][(size_t)((i*512 + (wave<<6))<<2)], lane);
    }
    f32x4 acc[2][8];
#pragma unroll
    for (int im = 0; im < 2; ++im)
#pragma unroll
        for (int in = 0; in < 8; ++in) {
            int col = wc*128 + in*16 + (lane & 15);
#pragma unroll
            for (int r = 0; r < 4; ++r) {
                int rl = wr*32 + im*16 + (lane >> 4)*4 + r;
                int grow = rowbase + rl;
                acc[im][in][r] = S1[(size_t)(grow >> 4)*256 + col]
                               + W1[(size_t)(256 + (grow & 15))*256 + col];
            }
        }
    __syncthreads();
#pragma unroll
    for (int kk = 0; kk < 2; ++kk) {
        f16x8 af[2], bf[8];
#pragma unroll
        for (int im = 0; im < 2; ++im) {
            int row = wr*32 + im*16 + (lane & 15);
            int ck = (kk*4 + (lane >> 4)) ^ (row & 7);
            af[im] = *(const f16x8*)(&wbuf[1][row*32 + ck*4]);
        }
#pragma unroll
        for (int in = 0; in < 8; ++in) {
            int n = wc*128 + in*16 + (lane & 15);
            int ck = (kk*4 + (lane >> 4)) ^ (n & 7);
            bf[in] = *(const f16x8*)(&wbuf[0][n*32 + ck*4]);
        }
#pragma unroll
        for (int im = 0; im < 2; ++im)
#pragma unroll
            for (int in = 0; in < 8; ++in)
                acc[im][in] = MFMA16(af[im], bf[in], acc[im][in]);
    }
#pragma unroll
    for (int im = 0; im < 2; ++im)
#pragma unroll
        for (int in = 0; in < 8; ++in) {
            int col = wc*128 + in*16 + (lane & 15);
            int chunk = col >> 3, pos = col & 7;
#pragma unroll
            for (int r = 0; r < 4; ++r) {
                int rl = wr*32 + im*16 + (lane >> 4)*4 + r;
                int swc = chunk ^ (rl & 7);
                *((_Float16*)x1s + rl*256 + swc*8 + pos) =
                    (_Float16)fmaxf(acc[im][in][r], 0.f);
                acc[im][in][r] = 0.f;
            }
        }
    __syncthreads();
    auto STAGE_W2 = [&](int buf, int kc) {
#pragma unroll
        for (int i = 0; i < 4; ++i) {
            int c = i*512 + tid;
            int row = c >> 3, kq = c & 7;
            gl_lds16(W2T16 + (size_t)row*128 + kc*32 + ((kq ^ (row&7))<<2),
                     &wbuf[buf][(size_t)((i*512 + (wave<<6))<<2)], lane);
        }
    };
    STAGE_W2(0, 0);
    __syncthreads();
    for (int kc = 0; kc < 4; ++kc) {
        int cur = kc & 1;
        if (kc + 1 < 4) STAGE_W2(cur ^ 1, kc + 1);
#pragma unroll
        for (int kk = 0; kk < 2; ++kk) {
            f16x8 af[2], bf[8];
#pragma unroll
            for (int im = 0; im < 2; ++im) {
                int row = wr*32 + im*16 + (lane & 15);
                int g = kc*8 + kk*4 + (lane >> 4);
                int ck = g ^ (row & 7);
                af[im] = *(const f16x8*)(&x1s[row*128 + ck*4]);
            }
#pragma unroll
            for (int in = 0; in < 8; ++in) {
                int n = wc*128 + in*16 + (lane & 15);
                int ck = (kk*4 + (lane >> 4)) ^ (n & 7);
                bf[in] = *(const f16x8*)(&wbuf[cur][n*32 + ck*4]);
            }
#pragma unroll
            for (int im = 0; im < 2; ++im)
#pragma unroll
                for (int in = 0; in < 8; ++in)
                    acc[im][in] = MFMA16(af[im], bf[in], acc[im][in]);
        }
        __syncthreads();
    }
    float w3v[8], b2v[8];
#pragma unroll
    for (int in = 0; in < 8; ++in) {
        int col = wc*128 + in*16 + (lane & 15);
        w3v[in] = W3[col]; b2v[in] = b2[col];
    }
#pragma unroll
    for (int im = 0; im < 2; ++im)
#pragma unroll
        for (int r = 0; r < 4; ++r) {
            float qp = 0.f;
#pragma unroll
            for (int in = 0; in < 8; ++in)
                qp = fmaf(fmaxf(acc[im][in][r] + b2v[in], 0.f), w3v[in], qp);
            qp += __shfl_xor(qp, 1);
            qp += __shfl_xor(qp, 2);
            qp += __shfl_xor(qp, 4);
            qp += __shfl_xor(qp, 8);
            if ((lane & 15) == 0)
                qpart[wr*32 + im*16 + (lane >> 4)*4 + r][wc] = qp;
        }
    __syncthreads();
    if (tid < 128)
        qout[rowbase + tid] = qpart[tid][0] + qpart[tid][1] + b3[0];
}

extern "C" void kernel_launch(void* const* d_in, const int* in_sizes, int n_in,
                              void* d_out, int out_size, void* d_ws, size_t ws_size,
                              hipStream_t stream)
{
    const float* state = (const float*)d_in[0];
    const float* obs   = (const float*)d_in[1];
    const float* Wx    = (const float*)d_in[2];
    const float* Wh    = (const float*)d_in[3];
    const float* b_gru = (const float*)d_in[4];
    const float* W_inc = (const float*)d_in[5];
    const float* b_inc = (const float*)d_in[6];
    const float* W_hg  = (const float*)d_in[7];
    const float* W1    = (const float*)d_in[8];
    const float* b1    = (const float*)d_in[9];
    const float* W2    = (const float*)d_in[10];
    const float* b2    = (const float*)d_in[11];
    const float* W3    = (const float*)d_in[12];
    const float* b3    = (const float*)d_in[13];
    float* qout   = (float*)d_out;
    float* graphs = (float*)d_out + NAR;

    float* base = (float*)d_ws;
    float* XG        = base;                              // 3,145,728 f
    float* hall      = base + 3145728;                    // 1,048,576 f
    float* S1        = base + 4194304;                    // 1,048,576 f
    uint32_t* emb_pk = (uint32_t*)(base + 5242880);       // 2,097,152 u32
    uint32_t* WhP    = (uint32_t*)(base + 7340032);       //    98,304 u32
    uint32_t* obs16  = (uint32_t*)(base + 7438336);       // 2,097,152 u32
    uint32_t* st16   = (uint32_t*)(base + 9535488);       //   524,288 u32
    uint32_t* WxT16  = (uint32_t*)(base + 10059776);      //   393,216 u32
    uint32_t* W1T16  = (uint32_t*)(base + 10452992);      //    32,768 u32
    uint32_t* W1eT16 = (uint32_t*)(base + 10485760);      //     8,192 u32
    uint32_t* W2T16  = (uint32_t*)(base + 10493952);      //    32,768 u32

    hipLaunchKernelGGL(k_prep_wh, dim3(384), dim3(256), 0, stream, Wh, WhP);
    hipLaunchKernelGGL(k_cvt_obs, dim3(2048), dim3(256), 0, stream, obs, obs16);
    hipLaunchKernelGGL(k_cvt_state, dim3(512), dim3(256), 0, stream, state, st16);
    hipLaunchKernelGGL(k_tr, dim3(16, 12), dim3(256), 0, stream, Wx, WxT16, 768, 512);
    hipLaunchKernelGGL(k_tr, dim3(4, 4), dim3(256), 0, stream, W1, W1T16, 256, 128);
    hipLaunchKernelGGL(k_tr, dim3(1, 4), dim3(256), 0, stream, W1 + 272*256, W1eT16, 256, 32);
    hipLaunchKernelGGL(k_tr, dim3(4, 4), dim3(256), 0, stream, W2, W2T16, 256, 128);
    hipLaunchKernelGGL(k_xg, dim3(192), dim3(256), 0, stream,
                       obs16, WxT16, b_gru, XG, 768, 1024, 6);
    hipLaunchKernelGGL(k_xg, dim3(64), dim3(256), 0, stream,
                       st16, W1T16, b1, S1, 256, 256, 2);
    hipLaunchKernelGGL(k_scan, dim3(32), dim3(512), 0, stream, WhP, XG, hall);
    hipLaunchKernelGGL(k_hyper, dim3(4096), dim3(256), 0, stream,
                       hall, obs, W_inc, b_inc, W_hg, graphs, emb_pk);
    hipLaunchKernelGGL(k_mlp, dim3(512), dim3(512), 0, stream,
                       emb_pk, S1, W1, W1eT16, W2T16, b2, W3, b3, qout);
}

// Round 7
// 262.861 us; speedup vs baseline: 1.0848x; 1.0127x over previous
//
#include <hip/hip_runtime.h>
#include <hip/hip_bf16.h>
#include <stdint.h>

#define BSZ 32
#define TT 128
#define NAG 16
#define NROW 4096
#define NAR 65536
#define EPSV 1e-6f

typedef __attribute__((ext_vector_type(2))) _Float16 half2v;
typedef _Float16 f16x8 __attribute__((ext_vector_type(8)));
typedef float f32x4 __attribute__((ext_vector_type(4)));

#define MFMA16(a,b,c) __builtin_amdgcn_mfma_f32_16x16x32_f16(a,b,c,0,0,0)

__device__ __forceinline__ float dot2f(uint32_t a, uint32_t b, float c) {
#if __has_builtin(__builtin_amdgcn_fdot2)
    return __builtin_amdgcn_fdot2(__builtin_bit_cast(half2v, a),
                                  __builtin_bit_cast(half2v, b), c, false);
#else
    half2v ha = __builtin_bit_cast(half2v, a);
    half2v hb = __builtin_bit_cast(half2v, b);
    return c + (float)ha.x*(float)hb.x + (float)ha.y*(float)hb.y;
#endif
}

__device__ __forceinline__ uint32_t packh2(float a, float b) {
    union { half2v h; uint32_t u; } cu;
    cu.h.x = (_Float16)a; cu.h.y = (_Float16)b;
    return cu.u;
}

__device__ __forceinline__ float sigm(float x) { return 1.f/(1.f + __expf(-x)); }
__device__ __forceinline__ float tanh_f(float x) { return 1.f - 2.f/(__expf(2.f*x) + 1.f); }

// async 16B global->LDS; dest = wave-uniform base + lane*16 (linear)
__device__ __forceinline__ void gl_lds16(const uint32_t* g, uint32_t* lwb, int lane) {
#if __has_builtin(__builtin_amdgcn_global_load_lds)
    __builtin_amdgcn_global_load_lds(
        (const __attribute__((address_space(1))) uint32_t*)g,
        (__attribute__((address_space(3))) uint32_t*)lwb, 16, 0, 0);
#else
    *(uint4*)(lwb + lane*4) = *(const uint4*)g;
#endif
}

// ---------------- K0: pack Wh for scan ----------------
// flat = kh*49152 + unit*16384 + g*1024 + u*4 + j  (kh:2, unit:3 gates, g:16, u:256, j:4)
// d = 4g + j (k-pair in half), k = kh*128 + 2d, c = unit*256 + u
// -> per-thread uint4 load (16B contiguous), coalesced across u.
__global__ void k_prep_wh(const float* __restrict__ Wh, uint32_t* __restrict__ WhP) {
    int g = blockIdx.x*256 + threadIdx.x;
    if (g >= 768*128) return;
    int kh = g / 49152;
    int r2 = g % 49152;
    int unit = r2 / 16384;
    int r3 = r2 % 16384;
    int gg = r3 >> 10;
    int r4 = r3 & 1023;
    int u = r4 >> 2;
    int j = r4 & 3;
    int k = kh*128 + 2*(gg*4 + j);
    int c = unit*256 + u;
    WhP[g] = packh2(Wh[(size_t)k*768 + c], Wh[(size_t)(k+1)*768 + c]);
}

// ---------------- cvt: obs -> f16 packed rows [4096][1024] ----
__global__ __launch_bounds__(256)
void k_cvt_obs(const float* __restrict__ obs, uint32_t* __restrict__ obs16) {
    int idx = blockIdx.x*256 + threadIdx.x;
    int r = idx >> 7, q = idx & 127;
    int a = q >> 3, f8 = (q & 7)*8;
    const float* p = obs + ((size_t)r*16 + a)*128 + f8;
    float4 v0 = *(const float4*)p, v1 = *(const float4*)(p+4);
    uint4 o; o.x=packh2(v0.x,v0.y); o.y=packh2(v0.z,v0.w);
    o.z=packh2(v1.x,v1.y); o.w=packh2(v1.z,v1.w);
    *(uint4*)(obs16 + (size_t)idx*4) = o;
}

// ---------------- cvt: state -> f16 [4096][256] ----------------
__global__ __launch_bounds__(256)
void k_cvt_state(const float* __restrict__ st, uint32_t* __restrict__ st16) {
    int idx = blockIdx.x*256 + threadIdx.x;
    int r = idx >> 5, q = idx & 31;
    const float* p = st + (size_t)r*256 + q*8;
    float4 v0 = *(const float4*)p, v1 = *(const float4*)(p+4);
    uint4 o; o.x=packh2(v0.x,v0.y); o.y=packh2(v0.z,v0.w);
    o.z=packh2(v1.x,v1.y); o.w=packh2(v1.z,v1.w);
    *(uint4*)(st16 + (size_t)idx*4) = o;
}

// ---------------- transpose+cvt: src f32 [K][N] -> out u32-packed [N][K/2] ----------
__global__ __launch_bounds__(256)
void k_tr(const float* __restrict__ src, uint32_t* __restrict__ out, int N, int Khalf) {
    __shared__ float t_[64][65];
    int k0 = blockIdx.x*64, n0 = blockIdx.y*64;
    int tid = threadIdx.x;
#pragma unroll
    for (int rep = 0; rep < 4; ++rep) {
        int idx = rep*256 + tid;
        int r = idx >> 4, c4 = (idx & 15)*4;
        float4 v = *(const float4*)(src + (size_t)(k0+r)*N + n0 + c4);
        t_[r][c4] = v.x; t_[r][c4+1] = v.y; t_[r][c4+2] = v.z; t_[r][c4+3] = v.w;
    }
    __syncthreads();
#pragma unroll
    for (int rep = 0; rep < 8; ++rep) {
        int idx = rep*256 + tid;
        int nl = idx >> 5, kp = idx & 31;
        out[(size_t)(n0+nl)*Khalf + (k0>>1) + kp] = packh2(t_[kp*2][nl], t_[kp*2+1][nl]);
    }
}

// ---------------- MFMA f16 GEMM: C[M,N] = A16[M,K] @ BT16[N,K]^T + bias ----------------
__global__ __launch_bounds__(256, 2)
void k_xg(const uint32_t* __restrict__ A16, const uint32_t* __restrict__ BT16,
          const float* __restrict__ bias, float* __restrict__ Cp,
          int N, int K, int nTilesN)
{
    __shared__ __align__(16) uint32_t lds[2][8192];
    int nwg = gridDim.x;
    int bid = blockIdx.x;
    int qq = nwg >> 3;
    int logical = (bid & 7)*qq + (bid >> 3);
    int bm = logical / nTilesN, bn = logical % nTilesN;
    int m0 = bm*128, n0 = bn*128;
    int tid = threadIdx.x;
    int lane = tid & 63, wave = tid >> 6;
    int wr = wave >> 1, wc = wave & 1;
    int Ku = K >> 1;

    f32x4 acc[4][4];
#pragma unroll
    for (int i = 0; i < 4; ++i)
#pragma unroll
        for (int j = 0; j < 4; ++j) acc[i][j] = (f32x4){0.f,0.f,0.f,0.f};

    auto STAGE = [&](int buf, int k0) {
#pragma unroll
        for (int i = 0; i < 8; ++i) {
            int c = i*256 + tid;
            int cr = c & 1023;
            int row = cr >> 3, kq = cr & 7;
            const uint32_t* src;
            if (c < 1024) src = A16 + (size_t)(m0+row)*Ku + (k0>>1) + ((kq ^ (row&7))<<2);
            else          src = BT16 + (size_t)(n0+row)*Ku + (k0>>1) + ((kq ^ (row&7))<<2);
            gl_lds16(src, &lds[buf][(size_t)((i*256 + (wave<<6))<<2)], lane);
        }
    };

    STAGE(0, 0);
    __syncthreads();
    int NT = K >> 6;
    for (int t = 0; t < NT; ++t) {
        int cur = t & 1;
        if (t + 1 < NT) STAGE(cur ^ 1, (t+1) << 6);
        const uint32_t* Ab = &lds[cur][0];
        const uint32_t* Bb = &lds[cur][4096];
#pragma unroll
        for (int kk = 0; kk < 2; ++kk) {
            f16x8 af[4], bf[4];
#pragma unroll
            for (int im = 0; im < 4; ++im) {
                int row = wr*64 + im*16 + (lane & 15);
                int ck = (kk*4 + (lane >> 4)) ^ (row & 7);
                af[im] = *(const f16x8*)(Ab + row*32 + ck*4);
            }
#pragma unroll
            for (int in = 0; in < 4; ++in) {
                int row = wc*64 + in*16 + (lane & 15);
                int ck = (kk*4 + (lane >> 4)) ^ (row & 7);
                bf[in] = *(const f16x8*)(Bb + row*32 + ck*4);
            }
#pragma unroll
            for (int im = 0; im < 4; ++im)
#pragma unroll
                for (int in = 0; in < 4; ++in)
                    acc[im][in] = MFMA16(af[im], bf[in], acc[im][in]);
        }
        __syncthreads();
    }
#pragma unroll
    for (int im = 0; im < 4; ++im)
#pragma unroll
        for (int in = 0; in < 4; ++in) {
            int col = n0 + wc*64 + in*16 + (lane & 15);
            float bv = bias[col];
#pragma unroll
            for (int r = 0; r < 4; ++r) {
                int row = m0 + wr*64 + im*16 + (lane >> 4)*4 + r;
                Cp[(size_t)row*N + col] = acc[im][in][r] + bv;
            }
        }
}

// ---------------- K2: GRU scan — 512 thr, weights as 48 named SSA uint4 (no alloca!) ----
// thread (kh=t>>8, u=t&255): gate cols {u, 256+u, 512+u} for k-half kh.
__global__ __launch_bounds__(512, 2)
void k_scan(const uint32_t* __restrict__ WhP, const float* __restrict__ XG,
            float* __restrict__ h_all)
{
    __shared__ float psum[2*768];
    __shared__ uint32_t h16s[128];     // h packed f16 pairs (2j, 2j+1)
    const int t = threadIdx.x;
    const int kh = t >> 8;
    const int u  = t & 255;
    const uint32_t* wp = WhP + kh*49152 + u*4;

#define LDW1(un, g) const uint4 W##un##_##g = *(const uint4*)(wp + un*16384 + g*1024);
#define LDW(g) LDW1(0, g) LDW1(1, g) LDW1(2, g)
    LDW(0) LDW(1) LDW(2) LDW(3) LDW(4) LDW(5) LDW(6) LDW(7)
    LDW(8) LDW(9) LDW(10) LDW(11) LDW(12) LDW(13) LDW(14) LDW(15)
#undef LDW
#undef LDW1

    if (t < 128) h16s[t] = 0u;
    float hreg = 0.f;
    const float* xp = XG + (size_t)blockIdx.x*TT*768 + u;
    float* hp = h_all + (size_t)blockIdx.x*TT*256 + u;
    float xgr = 0.f, xgz = 0.f, xgn = 0.f;
    if (t < 256) { xgr = xp[0]; xgz = xp[256]; xgn = xp[512]; }
    xp += 768;
    __syncthreads();
    for (int st = 0; st < TT; ++st) {
        // prefetch next step's gate inputs (last iter reads into hall region: defined, unused)
        float nr = 0.f, nz = 0.f, nn = 0.f;
        if (t < 256) { nr = xp[0]; nz = xp[256]; nn = xp[512]; }
        xp += 768;
        float a00=0.f,a01=0.f,a10=0.f,a11=0.f,a20=0.f,a21=0.f;
        const uint4* hq = (const uint4*)&h16s[kh*64];
#define GSTEP(g) { uint4 hv = hq[g]; \
        a00 = dot2f(hv.x, W0_##g.x, a00); a01 = dot2f(hv.y, W0_##g.y, a01); \
        a00 = dot2f(hv.z, W0_##g.z, a00); a01 = dot2f(hv.w, W0_##g.w, a01); \
        a10 = dot2f(hv.x, W1_##g.x, a10); a11 = dot2f(hv.y, W1_##g.y, a11); \
        a10 = dot2f(hv.z, W1_##g.z, a10); a11 = dot2f(hv.w, W1_##g.w, a11); \
        a20 = dot2f(hv.x, W2_##g.x, a20); a21 = dot2f(hv.y, W2_##g.y, a21); \
        a20 = dot2f(hv.z, W2_##g.z, a20); a21 = dot2f(hv.w, W2_##g.w, a21); }
        GSTEP(0) GSTEP(1) GSTEP(2) GSTEP(3) GSTEP(4) GSTEP(5) GSTEP(6) GSTEP(7)
        GSTEP(8) GSTEP(9) GSTEP(10) GSTEP(11) GSTEP(12) GSTEP(13) GSTEP(14) GSTEP(15)
#undef GSTEP
        psum[kh*768 + u]       = a00 + a01;
        psum[kh*768 + 256 + u] = a10 + a11;
        psum[kh*768 + 512 + u] = a20 + a21;
        __syncthreads();
        if (t < 256) {
            float hr = psum[u]       + psum[768 + u];
            float hz = psum[256 + u] + psum[768 + 256 + u];
            float hn = psum[512 + u] + psum[768 + 512 + u];
            float rg = sigm(xgr + hr);
            float zg = sigm(xgz + hz);
            float ng = tanh_f(xgn + rg*hn);
            float hnew = (1.f - zg)*ng + zg*hreg;
            hreg = hnew;
            union { _Float16 h; uint16_t v; } cu; cu.h = (_Float16)hnew;
            ((uint16_t*)h16s)[u] = cu.v;
            *hp = hnew;
        }
        hp += 256;
        __syncthreads();
        xgr = nr; xgz = nz; xgn = nn;
    }
}

// ---------------- K4: hypergraph conv (unchanged) ----------------
__global__ __launch_bounds__(256)
void k_hyper(const float* __restrict__ h_all, const float* __restrict__ obs,
             const float* __restrict__ W_inc, const float* __restrict__ b_inc,
             const float* __restrict__ W_hg,
             float* __restrict__ graphs, uint32_t* __restrict__ emb_pk)
{
    __shared__ float hs[256];
    __shared__ float hm[128];
    __shared__ float rdv[16];
    __shared__ float rde[8];
    __shared__ float xs[16][64];
    __shared__ float msg[8][64];
    __shared__ float outs[16][64];
    int r = blockIdx.x;
    int t = threadIdx.x;
    hs[t] = h_all[(size_t)r*256 + t];
    __syncthreads();
    if (t < 128) {
        float a = b_inc[t];
#pragma unroll 8
        for (int k = 0; k < 256; ++k) a = fmaf(hs[k], W_inc[k*128 + t], a);
        float s = sigm(a);
        hm[t] = s;
        graphs[(size_t)r*128 + t] = s;
    }
    __syncthreads();
    if (t < 16) {
        float s = EPSV;
#pragma unroll
        for (int e = 0; e < 8; ++e) s += hm[t*8 + e];
        rdv[t] = 1.f/sqrtf(s);
    } else if (t >= 64 && t < 72) {
        int e = t - 64;
        float s = EPSV;
#pragma unroll
        for (int a2 = 0; a2 < 16; ++a2) s += hm[a2*8 + e];
        rde[e] = 1.f/s;
    }
    __syncthreads();
    {
        int aa = t >> 4, f4 = t & 15;
        float4 v = *(const float4*)(obs + (size_t)r*2048 + aa*128 + f4*4);
        float sc = rdv[aa];
        *(float4*)&xs[aa][f4*4] = make_float4(v.x*sc, v.y*sc, v.z*sc, v.w*sc);
    }
    __syncthreads();
#pragma unroll
    for (int rep = 0; rep < 2; ++rep) {
        int o = rep*256 + t;
        int e = o >> 6, f = o & 63;
        float s = 0.f;
#pragma unroll
        for (int a2 = 0; a2 < 16; ++a2) s = fmaf(hm[a2*8 + e], xs[a2][f], s);
        msg[e][f] = s * rde[e];
    }
    __syncthreads();
#pragma unroll
    for (int rep = 0; rep < 4; ++rep) {
        int o = rep*256 + t;
        int a2 = o >> 6, f = o & 63;
        float s = 0.f;
#pragma unroll
        for (int e = 0; e < 8; ++e) s = fmaf(hm[a2*8 + e], msg[e][f], s);
        outs[a2][f] = s * rdv[a2];
    }
    __syncthreads();
    {
        int aa = t >> 4, fo0 = (t & 15)*4;
        float s0=0,s1=0,s2=0,s3=0;
#pragma unroll 8
        for (int f = 0; f < 64; ++f) {
            float ov = outs[aa][f];
            float4 wv = *(const float4*)(W_hg + f*64 + fo0);
            s0 = fmaf(ov, wv.x, s0); s1 = fmaf(ov, wv.y, s1);
            s2 = fmaf(ov, wv.z, s2); s3 = fmaf(ov, wv.w, s3);
        }
        s0 = fmaxf(s0,0.f); s1 = fmaxf(s1,0.f); s2 = fmaxf(s2,0.f); s3 = fmaxf(s3,0.f);
        uint2 pk; pk.x = packh2(s0, s1); pk.y = packh2(s2, s3);
        *(uint2*)&emb_pk[((size_t)r*16 + aa)*32 + (t & 15)*2] = pk;
    }
}

// ---------------- K5: fused MLP head, MFMA; 128 rows/block, 8 waves ----------------
__global__ __launch_bounds__(512, 2)
void k_mlp(const uint32_t* __restrict__ emb_pk, const float* __restrict__ S1,
           const float* __restrict__ W1, const uint32_t* __restrict__ W1eT16,
           const uint32_t* __restrict__ W2T16,
           const float* __restrict__ b2, const float* __restrict__ W3,
           const float* __restrict__ b3, float* __restrict__ qout)
{
    __shared__ __align__(16) uint32_t x1s[16384];
    __shared__ __align__(16) uint32_t wbuf[2][8192];
    __shared__ float qpart[128][2];
    int tid = threadIdx.x;
    int lane = tid & 63, wave = tid >> 6;
    int wr = wave >> 1, wc = wave & 1;
    int rowbase = blockIdx.x * 128;

#pragma unroll
    for (int i = 0; i < 4; ++i) {
        int c = i*512 + tid;
        int row = c >> 3, kq = c & 7;
        gl_lds16(W1eT16 + (size_t)row*32 + ((kq ^ (row&7))<<2),
                 &wbuf[0][(size_t)((i*512 + (wave<<6))<<2)], lane);
    }
#pragma unroll
    for (int i = 0; i < 2; ++i) {
        int c = i*512 + tid;
        int row = c >> 3, kq = c & 7;
        gl_lds16(emb_pk + (size_t)(rowbase+row)*32 + ((kq ^ (row&7))<<2),
                 &wbuf[1][(size_t)((i*512 + (wave<<6))<<2)], lane);
    }
    f32x4 acc[2][8];
#pragma unroll
    for (int im = 0; im < 2; ++im)
#pragma unroll
        for (int in = 0; in < 8; ++in) {
            int col = wc*128 + in*16 + (lane & 15);
#pragma unroll
            for (int r = 0; r < 4; ++r) {
                int rl = wr*32 + im*16 + (lane >> 4)*4 + r;
                int grow = rowbase + rl;
                acc[im][in][r] = S1[(size_t)(grow >> 4)*256 + col]
                               + W1[(size_t)(256 + (grow & 15))*256 + col];
            }
        }
    __syncthreads();
#pragma unroll
    for (int kk = 0; kk < 2; ++kk) {
        f16x8 af[2], bf[8];
#pragma unroll
        for (int im = 0; im < 2; ++im) {
            int row = wr*32 + im*16 + (lane & 15);
            int ck = (kk*4 + (lane >> 4)) ^ (row & 7);
            af[im] = *(const f16x8*)(&wbuf[1][row*32 + ck*4]);
        }
#pragma unroll
        for (int in = 0; in < 8; ++in) {
            int n = wc*128 + in*16 + (lane & 15);
            int ck = (kk*4 + (lane >> 4)) ^ (n & 7);
            bf[in] = *(const f16x8*)(&wbuf[0][n*32 + ck*4]);
        }
#pragma unroll
        for (int im = 0; im < 2; ++im)
#pragma unroll
            for (int in = 0; in < 8; ++in)
                acc[im][in] = MFMA16(af[im], bf[in], acc[im][in]);
    }
#pragma unroll
    for (int im = 0; im < 2; ++im)
#pragma unroll
        for (int in = 0; in < 8; ++in) {
            int col = wc*128 + in*16 + (lane & 15);
            int chunk = col >> 3, pos = col & 7;
#pragma unroll
            for (int r = 0; r < 4; ++r) {
                int rl = wr*32 + im*16 + (lane >> 4)*4 + r;
                int swc = chunk ^ (rl & 7);
                *((_Float16*)x1s + rl*256 + swc*8 + pos) =
                    (_Float16)fmaxf(acc[im][in][r], 0.f);
                acc[im][in][r] = 0.f;
            }
        }
    __syncthreads();
    auto STAGE_W2 = [&](int buf, int kc) {
#pragma unroll
        for (int i = 0; i < 4; ++i) {
            int c = i*512 + tid;
            int row = c >> 3, kq = c & 7;
            gl_lds16(W2T16 + (size_t)row*128 + kc*32 + ((kq ^ (row&7))<<2),
                     &wbuf[buf][(size_t)((i*512 + (wave<<6))<<2)], lane);
        }
    };
    STAGE_W2(0, 0);
    __syncthreads();
    for (int kc = 0; kc < 4; ++kc) {
        int cur = kc & 1;
        if (kc + 1 < 4) STAGE_W2(cur ^ 1, kc + 1);
#pragma unroll
        for (int kk = 0; kk < 2; ++kk) {
            f16x8 af[2], bf[8];
#pragma unroll
            for (int im = 0; im < 2; ++im) {
                int row = wr*32 + im*16 + (lane & 15);
                int g = kc*8 + kk*4 + (lane >> 4);
                int ck = g ^ (row & 7);
                af[im] = *(const f16x8*)(&x1s[row*128 + ck*4]);
            }
#pragma unroll
            for (int in = 0; in < 8; ++in) {
                int n = wc*128 + in*16 + (lane & 15);
                int ck = (kk*4 + (lane >> 4)) ^ (n & 7);
                bf[in] = *(const f16x8*)(&wbuf[cur][n*32 + ck*4]);
            }
#pragma unroll
            for (int im = 0; im < 2; ++im)
#pragma unroll
                for (int in = 0; in < 8; ++in)
                    acc[im][in] = MFMA16(af[im], bf[in], acc[im][in]);
        }
        __syncthreads();
    }
    float w3v[8], b2v[8];
#pragma unroll
    for (int in = 0; in < 8; ++in) {
        int col = wc*128 + in*16 + (lane & 15);
        w3v[in] = W3[col]; b2v[in] = b2[col];
    }
#pragma unroll
    for (int im = 0; im < 2; ++im)
#pragma unroll
        for (int r = 0; r < 4; ++r) {
            float qp = 0.f;
#pragma unroll
            for (int in = 0; in < 8; ++in)
                qp = fmaf(fmaxf(acc[im][in][r] + b2v[in], 0.f), w3v[in], qp);
            qp += __shfl_xor(qp, 1);
            qp += __shfl_xor(qp, 2);
            qp += __shfl_xor(qp, 4);
            qp += __shfl_xor(qp, 8);
            if ((lane & 15) == 0)
                qpart[wr*32 + im*16 + (lane >> 4)*4 + r][wc] = qp;
        }
    __syncthreads();
    if (tid < 128)
        qout[rowbase + tid] = qpart[tid][0] + qpart[tid][1] + b3[0];
}

extern "C" void kernel_launch(void* const* d_in, const int* in_sizes, int n_in,
                              void* d_out, int out_size, void* d_ws, size_t ws_size,
                              hipStream_t stream)
{
    const float* state = (const float*)d_in[0];
    const float* obs   = (const float*)d_in[1];
    const float* Wx    = (const float*)d_in[2];
    const float* Wh    = (const float*)d_in[3];
    const float* b_gru = (const float*)d_in[4];
    const float* W_inc = (const float*)d_in[5];
    const float* b_inc = (const float*)d_in[6];
    const float* W_hg  = (const float*)d_in[7];
    const float* W1    = (const float*)d_in[8];
    const float* b1    = (const float*)d_in[9];
    const float* W2    = (const float*)d_in[10];
    const float* b2    = (const float*)d_in[11];
    const float* W3    = (const float*)d_in[12];
    const float* b3    = (const float*)d_in[13];
    float* qout   = (float*)d_out;
    float* graphs = (float*)d_out + NAR;

    float* base = (float*)d_ws;
    float* XG        = base;                              // 3,145,728 f
    float* hall      = base + 3145728;                    // 1,048,576 f
    float* S1        = base + 4194304;                    // 1,048,576 f
    uint32_t* emb_pk = (uint32_t*)(base + 5242880);       // 2,097,152 u32
    uint32_t* WhP    = (uint32_t*)(base + 7340032);       //    98,304 u32
    uint32_t* obs16  = (uint32_t*)(base + 7438336);       // 2,097,152 u32
    uint32_t* st16   = (uint32_t*)(base + 9535488);       //   524,288 u32
    uint32_t* WxT16  = (uint32_t*)(base + 10059776);      //   393,216 u32
    uint32_t* W1T16  = (uint32_t*)(base + 10452992);      //    32,768 u32
    uint32_t* W1eT16 = (uint32_t*)(base + 10485760);      //     8,192 u32
    uint32_t* W2T16  = (uint32_t*)(base + 10493952);      //    32,768 u32

    hipLaunchKernelGGL(k_prep_wh, dim3(384), dim3(256), 0, stream, Wh, WhP);
    hipLaunchKernelGGL(k_cvt_obs, dim3(2048), dim3(256), 0, stream, obs, obs16);
    hipLaunchKernelGGL(k_cvt_state, dim3(512), dim3(256), 0, stream, state, st16);
    hipLaunchKernelGGL(k_tr, dim3(16, 12), dim3(256), 0, stream, Wx, WxT16, 768, 512);
    hipLaunchKernelGGL(k_tr, dim3(4, 4), dim3(256), 0, stream, W1, W1T16, 256, 128);
    hipLaunchKernelGGL(k_tr, dim3(1, 4), dim3(256), 0, stream, W1 + 272*256, W1eT16, 256, 32);
    hipLaunchKernelGGL(k_tr, dim3(4, 4), dim3(256), 0, stream, W2, W2T16, 256, 128);
    hipLaunchKernelGGL(k_xg, dim3(192), dim3(256), 0, stream,
                       obs16, WxT16, b_gru, XG, 768, 1024, 6);
    hipLaunchKernelGGL(k_xg, dim3(64), dim3(256), 0, stream,
                       st16, W1T16, b1, S1, 256, 256, 2);
    hipLaunchKernelGGL(k_scan, dim3(32), dim3(512), 0, stream, WhP, XG, hall);
    hipLaunchKernelGGL(k_hyper, dim3(4096), dim3(256), 0, stream,
                       hall, obs, W_inc, b_inc, W_hg, graphs, emb_pk);
    hipLaunchKernelGGL(k_mlp, dim3(512), dim3(512), 0, stream,
                       emb_pk, S1, W1, W1eT16, W2T16, b2, W3, b3, qout);
}